// Round 1
// baseline (1575.247 us; speedup 1.0000x reference)
//
#include <hip/hip_runtime.h>
#include <hip/hip_fp16.h>
#include <stdint.h>
#include <math.h>

// RegularizedSSM: fused spectral-norm (atomic-barrier persistent kernel) ->
// xb = x Bn^T -> Blelloch scan over t (bf16 A-op path + fp16 accumulator path)
// -> hs fp32 -> ys = hs Cn^T.   BK=64 GEMM (32 MFMA per barrier).
//
// R1: k_power restructured for latency: 32 blocks x 512 threads per matrix
// (was 8x1024), piggybacked norm partials (no redundant 1024-wide ssq trees),
// barriers cut 22 -> 20, sigma finalized inside k_cast_mats.

typedef unsigned short us;
typedef float  floatx4 __attribute__((ext_vector_type(4)));
typedef short  shortx8 __attribute__((ext_vector_type(8)));

#define HDIM 1024
#define MALL 32768   // B*T
#define PNB  32      // power-iteration blocks per matrix

__device__ __forceinline__ us f2bf(float f) {
  union { float f; unsigned u; } v; v.f = f;
  unsigned u = v.u;
  return (us)((u + 0x7FFFu + ((u >> 16) & 1u)) >> 16);   // RNE
}
__device__ __forceinline__ float bf2f(us h) {
  union { float f; unsigned u; } v; v.u = ((unsigned)h) << 16;
  return v.f;
}

__device__ __forceinline__ float bsum32(float t) {
  #pragma unroll
  for (int o = 16; o > 0; o >>= 1) t += __shfl_xor(t, o, 32);
  return t;
}

// ---------------- fused spectral norm: 32 blocks/matrix, atomic barrier ----------------
__device__ __forceinline__ void gbar(int* bar, int idx) {
  __threadfence();     // device-scope release of this block's prior writes
  __syncthreads();
  if (threadIdx.x == 0) {
    __hip_atomic_fetch_add(&bar[idx], 1, __ATOMIC_ACQ_REL, __HIP_MEMORY_SCOPE_AGENT);
    while (__hip_atomic_load(&bar[idx], __ATOMIC_ACQUIRE, __HIP_MEMORY_SCOPE_AGENT) < PNB)
      __builtin_amdgcn_s_sleep(2);
  }
  __syncthreads();
}

// grid (PNB, 3) x 512 threads.  um/vm hold RAW (unnormalized) vectors.
// part[m*1024 + it*32 + b]        = block b's partial ssq of v at A-phase it (it=0..10)
// part[m*1024 + 512 + it*32 + b]  = block b's partial ssq of u at B-phase it (it=0..9)
__global__ void k_power(const float* __restrict__ WA, const float* __restrict__ WB,
                        const float* __restrict__ WC,
                        float* __restrict__ uu, float* __restrict__ vv,
                        float* __restrict__ part, int* __restrict__ bar) {
  const int m = blockIdx.y, b = blockIdx.x, tid = threadIdx.x;
  const float* W = m == 0 ? WA : (m == 1 ? WB : WC);
  float* um = uu + m * 1024;
  float* vm = vv + m * 1024;
  float* PV = part + m * 1024;
  float* PU = part + m * 1024 + 512;
  int* barm = bar + m * 64;

  __shared__ __align__(16) float sh[1024];   // staged normalized vector
  __shared__ __align__(16) float red[512];
  __shared__ float bc;

  const int il = tid & 31, jp = tid >> 5;    // A: col-in-slice, row-group (16 x 64)
  const int jr = tid >> 4, ip = tid & 15;    // B: row-in-slice, k-lane

  for (int it = 0; it <= 10; ++it) {
    // ---- stage normalized u into sh ----
    if (it == 0) {
      ((float2*)sh)[tid] = make_float2(0.03125f, 0.03125f);   // u0 = 1/sqrt(1024), unit
      __syncthreads();
    } else {
      if (tid < 32) {
        float t = bsum32(PU[(it - 1) * 32 + tid]);
        if (tid == 0) bc = rsqrtf(t + 1e-24f);
      }
      __syncthreads();
      float su = bc;
      float2 u2 = ((const float2*)um)[tid];
      ((float2*)sh)[tid] = make_float2(u2.x * su, u2.y * su);
      __syncthreads();
    }

    // ---- phase A: v = W^T u_norm ; block owns cols [b*32, b*32+32) ----
    {
      const int col = b * 32 + il;
      const float* Wp = W + (size_t)(jp * 64) * 1024 + col;
      const float* up = sh + jp * 64;
      float a0 = 0.f, a1 = 0.f, a2 = 0.f, a3 = 0.f, a4 = 0.f, a5 = 0.f, a6 = 0.f, a7 = 0.f;
      #pragma unroll
      for (int j = 0; j < 64; j += 8) {
        a0 = fmaf(Wp[(size_t)(j + 0) * 1024], up[j + 0], a0);
        a1 = fmaf(Wp[(size_t)(j + 1) * 1024], up[j + 1], a1);
        a2 = fmaf(Wp[(size_t)(j + 2) * 1024], up[j + 2], a2);
        a3 = fmaf(Wp[(size_t)(j + 3) * 1024], up[j + 3], a3);
        a4 = fmaf(Wp[(size_t)(j + 4) * 1024], up[j + 4], a4);
        a5 = fmaf(Wp[(size_t)(j + 5) * 1024], up[j + 5], a5);
        a6 = fmaf(Wp[(size_t)(j + 6) * 1024], up[j + 6], a6);
        a7 = fmaf(Wp[(size_t)(j + 7) * 1024], up[j + 7], a7);
      }
      red[tid] = ((a0 + a1) + (a2 + a3)) + ((a4 + a5) + (a6 + a7));
      __syncthreads();
      if (tid < 32) {
        float s = 0.f;
        #pragma unroll
        for (int g = 0; g < 16; ++g) s += red[tid + 32 * g];
        vm[b * 32 + tid] = s;
        float t = bsum32(s * s);
        if (tid == 0) PV[it * 32 + b] = t;
      }
    }
    if (it == 10) break;            // sigma = sqrt(sum PV[10]); consumed by k_cast_mats
    gbar(barm, 2 * it);

    // ---- stage normalized v into sh ----
    if (tid < 32) {
      float t = bsum32(PV[it * 32 + tid]);
      if (tid == 0) bc = rsqrtf(t + 1e-24f);
    }
    __syncthreads();
    {
      float sv = bc;
      float2 v2 = ((const float2*)vm)[tid];
      ((float2*)sh)[tid] = make_float2(v2.x * sv, v2.y * sv);
    }
    __syncthreads();

    // ---- phase B: u = W v_norm ; block owns rows [b*32, b*32+32) ----
    {
      const int row = b * 32 + jr;
      const float* Wr = W + (size_t)row * 1024;
      float b0 = 0.f, b1 = 0.f, b2 = 0.f, b3 = 0.f, b4 = 0.f, b5 = 0.f, b6 = 0.f, b7 = 0.f;
      #pragma unroll
      for (int k = 0; k < 64; k += 8) {
        b0 = fmaf(Wr[ip + 16 * (k + 0)], sh[ip + 16 * (k + 0)], b0);
        b1 = fmaf(Wr[ip + 16 * (k + 1)], sh[ip + 16 * (k + 1)], b1);
        b2 = fmaf(Wr[ip + 16 * (k + 2)], sh[ip + 16 * (k + 2)], b2);
        b3 = fmaf(Wr[ip + 16 * (k + 3)], sh[ip + 16 * (k + 3)], b3);
        b4 = fmaf(Wr[ip + 16 * (k + 4)], sh[ip + 16 * (k + 4)], b4);
        b5 = fmaf(Wr[ip + 16 * (k + 5)], sh[ip + 16 * (k + 5)], b5);
        b6 = fmaf(Wr[ip + 16 * (k + 6)], sh[ip + 16 * (k + 6)], b6);
        b7 = fmaf(Wr[ip + 16 * (k + 7)], sh[ip + 16 * (k + 7)], b7);
      }
      float acc = ((b0 + b1) + (b2 + b3)) + ((b4 + b5) + (b6 + b7));
      acc += __shfl_down(acc, 8, 16);
      acc += __shfl_down(acc, 4, 16);
      acc += __shfl_down(acc, 2, 16);
      acc += __shfl_down(acc, 1, 16);
      if (ip == 0) { um[row] = acc; red[jr] = acc * acc; }
      __syncthreads();
      if (tid < 32) {
        float t = bsum32(red[tid]);
        if (tid == 0) PU[it * 32 + b] = t;
      }
    }
    gbar(barm, 2 * it + 1);
  }
}

// ---------------- casts ----------------
__global__ void k_cast_mats(const float* __restrict__ WA, const float* __restrict__ WB,
                            const float* __restrict__ WC, const float* __restrict__ part,
                            us* __restrict__ dst) {
  __shared__ float bcs;
  const int m = (int)(((unsigned)blockIdx.x * 256u) >> 18);
  if (threadIdx.x < 32) {
    float t = bsum32(part[m * 1024 + 10 * 32 + threadIdx.x]);   // ssq of final v_raw
    if (threadIdx.x == 0) bcs = rsqrtf(t + 1e-24f);             // 1/sigma
  }
  __syncthreads();
  float rs = bcs;
  int idx = blockIdx.x * 256 + threadIdx.x;
  const float* W = m == 0 ? WA : (m == 1 ? WB : WC);
  float4 v = ((const float4*)W)[idx & 262143];
  unsigned lo = f2bf(v.x * rs) | ((unsigned)f2bf(v.y * rs) << 16);
  unsigned hi = f2bf(v.z * rs) | ((unsigned)f2bf(v.w * rs) << 16);
  ((uint2*)dst)[idx] = make_uint2(lo, hi);
}

__global__ void k_cast_x(const float* __restrict__ src, us* __restrict__ dst, int n4) {
  int idx = blockIdx.x * 256 + threadIdx.x;
  int stride = gridDim.x * 256;
  for (; idx < n4; idx += stride) {
    float4 v = ((const float4*)src)[idx];
    unsigned lo = f2bf(v.x) | ((unsigned)f2bf(v.y) << 16);
    unsigned hi = f2bf(v.z) | ((unsigned)f2bf(v.w) << 16);
    ((uint2*)dst)[idx] = make_uint2(lo, hi);
  }
}

// bf16 1024x1024 transpose
__global__ void k_transpose(const us* __restrict__ src, us* __restrict__ dst) {
  __shared__ us t[32][33];
  int bx = blockIdx.x * 32, by = blockIdx.y * 32;
  int tx = threadIdx.x & 31, ty = threadIdx.x >> 5;
  for (int r = ty; r < 32; r += 8)
    t[r][tx] = src[(size_t)(by + r) * 1024 + bx + tx];
  __syncthreads();
  for (int r = ty; r < 32; r += 8)
    dst[(size_t)(bx + r) * 1024 + by + tx] = t[tx][r];
}

// ---------------- GEMM: C[m,n] = sum_k Aop[m,k]*B[n,k] (+acc-init), BK=64 ----------------
// accmode: 0 zero, 2 bf16 acc, 3 fp16 acc.
template <int TILE>
__global__ __launch_bounds__(256, 3)
void k_gemm(const us* __restrict__ Abf, const us* __restrict__ Bmat,
            const us* __restrict__ AccP,
            float* __restrict__ Out32, us* __restrict__ Out16, us* __restrict__ OutH,
            us* __restrict__ Copy16,
            int M, int stride_log, int delta_a, int delta_acc, int delta_copy,
            int accmode, int zero_aop) {
  constexpr int BK = 64;
  constexpr int WT = TILE / 2;   // wave tile
  constexpr int NT = WT / 16;    // mfma tiles per wave dim
  constexpr int QA = TILE / 32;  // 16B staging chunks per thread per operand

  __shared__ us ldsA[TILE * BK];
  __shared__ us ldsB[TILE * BK];

  const int tid = threadIdx.x;
  const int wave = tid >> 6, lane = tid & 63;
  const int wr = wave >> 1, wc = wave & 1;
  const int lr = lane & 15, g = lane >> 4;
  const int m0 = blockIdx.x * TILE, n0 = blockIdx.y * TILE;

  const int cnt_log = 10 - stride_log;
  const int cnt_mask = (1 << cnt_log) - 1;
  auto rowC = [&](int m) -> int {
    int j = m & cnt_mask, b = m >> cnt_log;
    return (b << 10) + (((j + 1) << stride_log) - 1);
  };

  floatx4 acc[NT][NT];
  if (accmode == 0) {
    #pragma unroll
    for (int i = 0; i < NT; ++i)
      #pragma unroll
      for (int j = 0; j < NT; ++j) acc[i][j] = (floatx4)(0.0f);
  } else {
    #pragma unroll
    for (int ii = 0; ii < NT; ++ii) {
      #pragma unroll
      for (int r = 0; r < 4; ++r) {
        int m = m0 + wr * WT + ii * 16 + g * 4 + r;
        if (m >= M) m = M - 1;
        size_t rowoff = (size_t)(rowC(m) - delta_acc) * HDIM;
        #pragma unroll
        for (int jj = 0; jj < NT; ++jj) {
          int col = n0 + wc * WT + jj * 16 + lr;
          us raw = AccP[rowoff + col];
          acc[ii][jj][r] = (accmode == 2) ? bf2f(raw)
                                          : __half2float(*(const __half*)&raw);
        }
      }
    }
  }

  if (!zero_aop) {
    // chunk ch = tid + q*256 -> row i = ch>>3, physical slot p = ch&7,
    // logical k-chunk c = p ^ s(i), s(i)=(i>>1)&7 (2-way-per-bank on ds_read_b128).
    size_t abase[QA], bbase[QA];
    #pragma unroll
    for (int q = 0; q < QA; ++q) {
      int ch = tid + q * 256;
      int i = ch >> 3;
      int c = (ch & 7) ^ ((i >> 1) & 7);
      int m = m0 + i; if (m >= M) m = M - 1;
      abase[q] = (size_t)(rowC(m) - delta_a) * HDIM + c * 8;
      bbase[q] = (size_t)(n0 + i) * HDIM + c * 8;
    }
    for (int k0 = 0; k0 < HDIM; k0 += BK) {
      __syncthreads();
      #pragma unroll
      for (int q = 0; q < QA; ++q) {
        __builtin_amdgcn_global_load_lds(
            (const __attribute__((address_space(1))) void*)(Abf + abase[q] + k0),
            (__attribute__((address_space(3))) void*)(ldsA + (wave * 64 + q * 256) * 8),
            16, 0, 0);
        __builtin_amdgcn_global_load_lds(
            (const __attribute__((address_space(1))) void*)(Bmat + bbase[q] + k0),
            (__attribute__((address_space(3))) void*)(ldsB + (wave * 64 + q * 256) * 8),
            16, 0, 0);
      }
      __syncthreads();
      #pragma unroll
      for (int kk = 0; kk < 2; ++kk) {
        shortx8 af[NT], bfv[NT];
        #pragma unroll
        for (int ii = 0; ii < NT; ++ii) {
          int ra = wr * WT + ii * 16 + lr;
          af[ii] = *(const shortx8*)(ldsA + ra * BK + (((kk * 4 + g) ^ ((ra >> 1) & 7)) * 8));
          int rb = wc * WT + ii * 16 + lr;
          bfv[ii] = *(const shortx8*)(ldsB + rb * BK + (((kk * 4 + g) ^ ((rb >> 1) & 7)) * 8));
        }
        #pragma unroll
        for (int ii = 0; ii < NT; ++ii)
          #pragma unroll
          for (int jj = 0; jj < NT; ++jj)
            acc[ii][jj] = __builtin_amdgcn_mfma_f32_16x16x32_bf16(af[ii], bfv[jj], acc[ii][jj], 0, 0, 0);
      }
    }
  }

  // epilogue: C/D layout col = lane&15, row = (lane>>4)*4 + reg
  #pragma unroll
  for (int ii = 0; ii < NT; ++ii) {
    #pragma unroll
    for (int r = 0; r < 4; ++r) {
      int m = m0 + wr * WT + ii * 16 + g * 4 + r;
      if (m >= M) continue;
      size_t rowoff = (size_t)rowC(m) * HDIM;
      #pragma unroll
      for (int jj = 0; jj < NT; ++jj) {
        int col = n0 + wc * WT + jj * 16 + lr;
        float v = acc[ii][jj][r];
        if (Copy16) {
          us pv = zero_aop ? (us)0 : Abf[rowoff + col];
          Copy16[(size_t)(rowC(m) - delta_copy) * HDIM + col] = pv;
        }
        if (Out32) Out32[rowoff + col] = v;
        if (Out16) Out16[rowoff + col] = f2bf(v);
        if (OutH) {
          __half hv = __float2half(v);
          OutH[rowoff + col] = *(const us*)&hv;
        }
      }
    }
  }
}

// ---------------- launch ----------------
extern "C" void kernel_launch(void* const* d_in, const int* in_sizes, int n_in,
                              void* d_out, int out_size, void* d_ws, size_t ws_size,
                              hipStream_t stream) {
  const float* x  = (const float*)d_in[0];
  const float* WA = (const float*)d_in[1];
  const float* WB = (const float*)d_in[2];
  const float* WC = (const float*)d_in[3];

  float* ys = (float*)d_out;                     // [32768,1024]
  float* U  = ys + (size_t)MALL * HDIM;          // hs region (also down-sweep ping A)
  us* U16 = (us*)U;

  char* wsb = (char*)d_ws;
  int*   bar  = (int*)(wsb);                     // 3*64 barrier counters
  float* uu   = (float*)(wsb + 4096);            // 3*1024
  float* vv   = (float*)(wsb + 20480);           // 3*1024
  float* part = (float*)(wsb + 32768);           // 3*1024 norm partials
  us* An = (us*)(wsb + 65536);                   // An,Bn,Cn contiguous
  us* Bn = An + 1048576;
  us* Cn = Bn + 1048576;
  us* PT = Cn + 1048576;                         // transpose scratch + powers
  us* Ppow[9];
  Ppow[0] = An;
  for (int d = 1; d <= 8; ++d) Ppow[d] = PT + (size_t)d * 1048576;
  us* Xbf  = (us*)(wsb + 25231360);              // 64MB: x bf16, then fp16 node buffer Uh
  us* Uh   = Xbf;                                //       (x dead after step 4)
  us* U0bf = Xbf + (size_t)MALL * HDIM;          // 64MB: xb bf16; later Hbf mirror
  us* Ubf  = U0bf + (size_t)MALL * HDIM;         // 64MB: up-sweep node bf16 / ping B
  if (ws_size < 226643968ULL) return;

  auto gemm = [&](int tile, const us* A, const us* B, const us* accP,
                  float* o32, us* o16, us* oH, us* cp16,
                  int M, int slog, int da, int dacc, int dcp, int am, int za) {
    dim3 grid((M + tile - 1) / tile, HDIM / tile);
    if (tile == 128)
      k_gemm<128><<<grid, 256, 0, stream>>>(A, B, accP, o32, o16, oH, cp16, M, slog, da, dacc, dcp, am, za);
    else
      k_gemm<64><<<grid, 256, 0, stream>>>(A, B, accP, o32, o16, oH, cp16, M, slog, da, dacc, dcp, am, za);
  };

  // 1) spectral norms (one persistent kernel; barrier counters zeroed per call)
  hipMemsetAsync(bar, 0, 3 * 64 * sizeof(int), stream);
  k_power<<<dim3(PNB, 3), 512, 0, stream>>>(WA, WB, WC, uu, vv, part, bar);

  // 2) casts (1/sigma folded in; sigma finalized from partials inside k_cast_mats)
  k_cast_mats<<<dim3(3072), 256, 0, stream>>>(WA, WB, WC, part, An);
  k_cast_x<<<dim3(8192), 256, 0, stream>>>(x, Xbf, 8388608);

  // 3) power chain A^(2^d), d=1..8
  for (int d = 1; d <= 8; ++d) {
    k_transpose<<<dim3(32, 32), 256, 0, stream>>>(Ppow[d - 1], PT);
    gemm(64, Ppow[d - 1], PT, nullptr, nullptr, Ppow[d], nullptr, nullptr,
         1024, 0, 0, 0, 0, 0, 0);
  }

  // 4) xb = x Bn^T -> U0bf (bf16 only)
  gemm(128, Xbf, Bn, nullptr, nullptr, U0bf, nullptr, nullptr, MALL, 0, 0, 0, 0, 0, 0);

  // 5) up-sweep: node = A^(2^d) * left + right ; bf16 nodes -> Ubf, fp16 nodes -> Uh
  for (int d = 0; d <= 8; ++d) {
    int M = MALL >> (d + 1);
    const us* srcA = (d == 0) ? U0bf : Ubf;
    const us* accP = (d == 0) ? U0bf : Uh;
    int am = (d == 0) ? 2 : 3;
    gemm(M >= 2048 ? 128 : 64, srcA, Ppow[d], accP, nullptr, Ubf, Uh, nullptr,
         M, d + 1, 1 << d, 0, 0, am, 0);
  }

  // 6) down-sweep: prefix_right = A^(2^d) prefix_par + up_left; prefix_left = prefix_par
  //    ping-pong U16 (d_out hs region) <-> Ubf; additive from Uh fp16 (U0bf bf16 at d=0)
  {
    us* PP2[2] = {U16, Ubf};        // idx even -> U16, idx odd -> Ubf; idx9 dst = Ubf
    for (int idx = 0; idx <= 9; ++idx) {
      int d = 9 - idx;
      int M = MALL >> (d + 1);
      const us* srcA = idx ? PP2[(idx - 1) & 1] : nullptr;
      us* dst = PP2[idx & 1];
      const us* accP = (d == 0) ? U0bf : Uh;
      int am = (d == 0) ? 2 : 3;
      gemm(M >= 2048 ? 128 : 64, srcA, Ppow[d], accP,
           nullptr, dst, nullptr, dst,
           M, d + 1, 0, 1 << d, 1 << d, am, idx == 0 ? 1 : 0);
    }
  }

  // 7) final apply: h_t = An * p_t + xb_t  (p in Ubf, xb in U0bf) -> hs fp32 + Hbf(->U0bf)
  gemm(128, Ubf, An, U0bf, U, U0bf, nullptr, nullptr, MALL, 0, 0, 0, 0, 2, 0);

  // 8) ys = hs Cn^T
  gemm(128, U0bf, Cn, nullptr, ys, nullptr, nullptr, nullptr, MALL, 0, 0, 0, 0, 0, 0);
}

// Round 2
// 1337.585 us; speedup vs baseline: 1.1777x; 1.1777x over previous
//
#include <hip/hip_runtime.h>
#include <hip/hip_fp16.h>
#include <stdint.h>
#include <math.h>

// RegularizedSSM: fused spectral-norm (flag-barrier persistent kernel) ->
// xb = x Bn^T -> Blelloch scan over t (bf16 A-op path + fp16 accumulator path)
// -> hs fp32 -> ys = hs Cn^T.   BK=64 GEMM (32 MFMA per barrier).
//
// R2: k_power barrier rebuilt cache-maintenance-free. All cross-block traffic
// (um/vm/partials/flags) moves via agent-scope RELAXED atomics (L2-bypass, no
// buffer_inv / buffer_wbl2), barrier is flag-per-block + ballot poll (no RMW
// serialization). W stays warm in L2 across all 21 phases.

typedef unsigned short us;
typedef float  floatx4 __attribute__((ext_vector_type(4)));
typedef short  shortx8 __attribute__((ext_vector_type(8)));

#define HDIM 1024
#define MALL 32768   // B*T
#define PNB  32      // power-iteration blocks per matrix

__device__ __forceinline__ us f2bf(float f) {
  union { float f; unsigned u; } v; v.f = f;
  unsigned u = v.u;
  return (us)((u + 0x7FFFu + ((u >> 16) & 1u)) >> 16);   // RNE
}
__device__ __forceinline__ float bf2f(us h) {
  union { float f; unsigned u; } v; v.u = ((unsigned)h) << 16;
  return v.f;
}

__device__ __forceinline__ float bsum32(float t) {
  #pragma unroll
  for (int o = 16; o > 0; o >>= 1) t += __shfl_xor(t, o, 32);
  return t;
}

// ---- agent-scope coherent (L2-bypass) accessors: no cache maintenance ----
__device__ __forceinline__ float gload(const float* p) {
  return __hip_atomic_load((float*)p, __ATOMIC_RELAXED, __HIP_MEMORY_SCOPE_AGENT);
}
__device__ __forceinline__ float2 gload2(const float* p) {
  unsigned long long r = __hip_atomic_load((unsigned long long*)p,
                                           __ATOMIC_RELAXED, __HIP_MEMORY_SCOPE_AGENT);
  union { unsigned long long u; float2 f; } v; v.u = r; return v.f;
}
__device__ __forceinline__ void gstore(float* p, float x) {
  __hip_atomic_store(p, x, __ATOMIC_RELAXED, __HIP_MEMORY_SCOPE_AGENT);
}

// Flag barrier: block b publishes phase number; 32 lanes poll the 32 flags.
// Ordering: __syncthreads() drains vmcnt(0) (bypass stores ack'd at coherence
// point) before the flag store; consumers read data via bypass loads only.
__device__ __forceinline__ void gbar(int* flag, int b, int phase) {
  const int tid = threadIdx.x;
  __syncthreads();
  if (tid == 0)
    __hip_atomic_store(flag + b, phase, __ATOMIC_RELAXED, __HIP_MEMORY_SCOPE_AGENT);
  if (tid < PNB) {
    for (;;) {
      int f = __hip_atomic_load(flag + tid, __ATOMIC_RELAXED, __HIP_MEMORY_SCOPE_AGENT);
      if (__ballot(f < phase) == 0ULL) break;
      __builtin_amdgcn_s_sleep(2);
    }
  }
  __syncthreads();
}

// grid (PNB, 3) x 512 threads.  um/vm hold RAW (unnormalized) vectors.
// part[m*1024 + it*32 + b]        = block b's partial ssq of v at A-phase it (it=0..10)
// part[m*1024 + 512 + it*32 + b]  = block b's partial ssq of u at B-phase it (it=0..9)
__global__ void k_power(const float* __restrict__ WA, const float* __restrict__ WB,
                        const float* __restrict__ WC,
                        float* __restrict__ uu, float* __restrict__ vv,
                        float* __restrict__ part, int* __restrict__ bar) {
  const int m = blockIdx.y, b = blockIdx.x, tid = threadIdx.x;
  const float* W = m == 0 ? WA : (m == 1 ? WB : WC);
  float* um = uu + m * 1024;
  float* vm = vv + m * 1024;
  float* PV = part + m * 1024;
  float* PU = part + m * 1024 + 512;
  int* flag = bar + m * PNB;

  __shared__ __align__(16) float sh[1024];   // staged normalized vector
  __shared__ __align__(16) float red[512];
  __shared__ float bc;

  const int il = tid & 31, jp = tid >> 5;    // A: col-in-slice, row-group (16 x 64)
  const int jr = tid >> 4, ip = tid & 15;    // B: row-in-slice, k-lane

  int ph = 0;
  for (int it = 0; it <= 10; ++it) {
    // ---- stage normalized u into sh ----
    if (it == 0) {
      ((float2*)sh)[tid] = make_float2(0.03125f, 0.03125f);   // u0 = 1/sqrt(1024), unit
      __syncthreads();
    } else {
      if (tid < 32) {
        float t = bsum32(gload(PU + (it - 1) * 32 + tid));
        if (tid == 0) bc = rsqrtf(t + 1e-24f);
      }
      __syncthreads();
      float su = bc;
      float2 u2 = gload2(um + tid * 2);
      ((float2*)sh)[tid] = make_float2(u2.x * su, u2.y * su);
      __syncthreads();
    }

    // ---- phase A: v = W^T u_norm ; block owns cols [b*32, b*32+32) ----
    {
      const int col = b * 32 + il;
      const float* Wp = W + (size_t)(jp * 64) * 1024 + col;
      const float* up = sh + jp * 64;
      float a0 = 0.f, a1 = 0.f, a2 = 0.f, a3 = 0.f, a4 = 0.f, a5 = 0.f, a6 = 0.f, a7 = 0.f;
      #pragma unroll
      for (int j = 0; j < 64; j += 8) {
        a0 = fmaf(Wp[(size_t)(j + 0) * 1024], up[j + 0], a0);
        a1 = fmaf(Wp[(size_t)(j + 1) * 1024], up[j + 1], a1);
        a2 = fmaf(Wp[(size_t)(j + 2) * 1024], up[j + 2], a2);
        a3 = fmaf(Wp[(size_t)(j + 3) * 1024], up[j + 3], a3);
        a4 = fmaf(Wp[(size_t)(j + 4) * 1024], up[j + 4], a4);
        a5 = fmaf(Wp[(size_t)(j + 5) * 1024], up[j + 5], a5);
        a6 = fmaf(Wp[(size_t)(j + 6) * 1024], up[j + 6], a6);
        a7 = fmaf(Wp[(size_t)(j + 7) * 1024], up[j + 7], a7);
      }
      red[tid] = ((a0 + a1) + (a2 + a3)) + ((a4 + a5) + (a6 + a7));
      __syncthreads();
      if (tid < 32) {
        float s = 0.f;
        #pragma unroll
        for (int g = 0; g < 16; ++g) s += red[tid + 32 * g];
        gstore(vm + b * 32 + tid, s);
        float t = bsum32(s * s);
        if (tid == 0) gstore(PV + it * 32 + b, t);
      }
    }
    if (it == 10) break;            // sigma = sqrt(sum PV[10]); consumed by k_cast_mats
    gbar(flag, b, ++ph);

    // ---- stage normalized v into sh ----
    if (tid < 32) {
      float t = bsum32(gload(PV + it * 32 + tid));
      if (tid == 0) bc = rsqrtf(t + 1e-24f);
    }
    __syncthreads();
    {
      float sv = bc;
      float2 v2 = gload2(vm + tid * 2);
      ((float2*)sh)[tid] = make_float2(v2.x * sv, v2.y * sv);
    }
    __syncthreads();

    // ---- phase B: u = W v_norm ; block owns rows [b*32, b*32+32) ----
    {
      const int row = b * 32 + jr;
      const float* Wr = W + (size_t)row * 1024;
      float b0 = 0.f, b1 = 0.f, b2 = 0.f, b3 = 0.f, b4 = 0.f, b5 = 0.f, b6 = 0.f, b7 = 0.f;
      #pragma unroll
      for (int k = 0; k < 64; k += 8) {
        b0 = fmaf(Wr[ip + 16 * (k + 0)], sh[ip + 16 * (k + 0)], b0);
        b1 = fmaf(Wr[ip + 16 * (k + 1)], sh[ip + 16 * (k + 1)], b1);
        b2 = fmaf(Wr[ip + 16 * (k + 2)], sh[ip + 16 * (k + 2)], b2);
        b3 = fmaf(Wr[ip + 16 * (k + 3)], sh[ip + 16 * (k + 3)], b3);
        b4 = fmaf(Wr[ip + 16 * (k + 4)], sh[ip + 16 * (k + 4)], b4);
        b5 = fmaf(Wr[ip + 16 * (k + 5)], sh[ip + 16 * (k + 5)], b5);
        b6 = fmaf(Wr[ip + 16 * (k + 6)], sh[ip + 16 * (k + 6)], b6);
        b7 = fmaf(Wr[ip + 16 * (k + 7)], sh[ip + 16 * (k + 7)], b7);
      }
      float acc = ((b0 + b1) + (b2 + b3)) + ((b4 + b5) + (b6 + b7));
      acc += __shfl_down(acc, 8, 16);
      acc += __shfl_down(acc, 4, 16);
      acc += __shfl_down(acc, 2, 16);
      acc += __shfl_down(acc, 1, 16);
      if (ip == 0) { gstore(um + row, acc); red[jr] = acc * acc; }
      __syncthreads();
      if (tid < 32) {
        float t = bsum32(red[tid]);
        if (tid == 0) gstore(PU + it * 32 + b, t);
      }
    }
    gbar(flag, b, ++ph);
  }
}

// ---------------- casts ----------------
__global__ void k_cast_mats(const float* __restrict__ WA, const float* __restrict__ WB,
                            const float* __restrict__ WC, const float* __restrict__ part,
                            us* __restrict__ dst) {
  __shared__ float bcs;
  const int m = (int)(((unsigned)blockIdx.x * 256u) >> 18);
  if (threadIdx.x < 32) {
    float t = bsum32(part[m * 1024 + 10 * 32 + threadIdx.x]);   // ssq of final v_raw
    if (threadIdx.x == 0) bcs = rsqrtf(t + 1e-24f);             // 1/sigma
  }
  __syncthreads();
  float rs = bcs;
  int idx = blockIdx.x * 256 + threadIdx.x;
  const float* W = m == 0 ? WA : (m == 1 ? WB : WC);
  float4 v = ((const float4*)W)[idx & 262143];
  unsigned lo = f2bf(v.x * rs) | ((unsigned)f2bf(v.y * rs) << 16);
  unsigned hi = f2bf(v.z * rs) | ((unsigned)f2bf(v.w * rs) << 16);
  ((uint2*)dst)[idx] = make_uint2(lo, hi);
}

__global__ void k_cast_x(const float* __restrict__ src, us* __restrict__ dst, int n4) {
  int idx = blockIdx.x * 256 + threadIdx.x;
  int stride = gridDim.x * 256;
  for (; idx < n4; idx += stride) {
    float4 v = ((const float4*)src)[idx];
    unsigned lo = f2bf(v.x) | ((unsigned)f2bf(v.y) << 16);
    unsigned hi = f2bf(v.z) | ((unsigned)f2bf(v.w) << 16);
    ((uint2*)dst)[idx] = make_uint2(lo, hi);
  }
}

// bf16 1024x1024 transpose
__global__ void k_transpose(const us* __restrict__ src, us* __restrict__ dst) {
  __shared__ us t[32][33];
  int bx = blockIdx.x * 32, by = blockIdx.y * 32;
  int tx = threadIdx.x & 31, ty = threadIdx.x >> 5;
  for (int r = ty; r < 32; r += 8)
    t[r][tx] = src[(size_t)(by + r) * 1024 + bx + tx];
  __syncthreads();
  for (int r = ty; r < 32; r += 8)
    dst[(size_t)(bx + r) * 1024 + by + tx] = t[tx][r];
}

// ---------------- GEMM: C[m,n] = sum_k Aop[m,k]*B[n,k] (+acc-init), BK=64 ----------------
// accmode: 0 zero, 2 bf16 acc, 3 fp16 acc.
template <int TILE>
__global__ __launch_bounds__(256, 3)
void k_gemm(const us* __restrict__ Abf, const us* __restrict__ Bmat,
            const us* __restrict__ AccP,
            float* __restrict__ Out32, us* __restrict__ Out16, us* __restrict__ OutH,
            us* __restrict__ Copy16,
            int M, int stride_log, int delta_a, int delta_acc, int delta_copy,
            int accmode, int zero_aop) {
  constexpr int BK = 64;
  constexpr int WT = TILE / 2;   // wave tile
  constexpr int NT = WT / 16;    // mfma tiles per wave dim
  constexpr int QA = TILE / 32;  // 16B staging chunks per thread per operand

  __shared__ us ldsA[TILE * BK];
  __shared__ us ldsB[TILE * BK];

  const int tid = threadIdx.x;
  const int wave = tid >> 6, lane = tid & 63;
  const int wr = wave >> 1, wc = wave & 1;
  const int lr = lane & 15, g = lane >> 4;
  const int m0 = blockIdx.x * TILE, n0 = blockIdx.y * TILE;

  const int cnt_log = 10 - stride_log;
  const int cnt_mask = (1 << cnt_log) - 1;
  auto rowC = [&](int m) -> int {
    int j = m & cnt_mask, b = m >> cnt_log;
    return (b << 10) + (((j + 1) << stride_log) - 1);
  };

  floatx4 acc[NT][NT];
  if (accmode == 0) {
    #pragma unroll
    for (int i = 0; i < NT; ++i)
      #pragma unroll
      for (int j = 0; j < NT; ++j) acc[i][j] = (floatx4)(0.0f);
  } else {
    #pragma unroll
    for (int ii = 0; ii < NT; ++ii) {
      #pragma unroll
      for (int r = 0; r < 4; ++r) {
        int m = m0 + wr * WT + ii * 16 + g * 4 + r;
        if (m >= M) m = M - 1;
        size_t rowoff = (size_t)(rowC(m) - delta_acc) * HDIM;
        #pragma unroll
        for (int jj = 0; jj < NT; ++jj) {
          int col = n0 + wc * WT + jj * 16 + lr;
          us raw = AccP[rowoff + col];
          acc[ii][jj][r] = (accmode == 2) ? bf2f(raw)
                                          : __half2float(*(const __half*)&raw);
        }
      }
    }
  }

  if (!zero_aop) {
    // chunk ch = tid + q*256 -> row i = ch>>3, physical slot p = ch&7,
    // logical k-chunk c = p ^ s(i), s(i)=(i>>1)&7 (2-way-per-bank on ds_read_b128).
    size_t abase[QA], bbase[QA];
    #pragma unroll
    for (int q = 0; q < QA; ++q) {
      int ch = tid + q * 256;
      int i = ch >> 3;
      int c = (ch & 7) ^ ((i >> 1) & 7);
      int m = m0 + i; if (m >= M) m = M - 1;
      abase[q] = (size_t)(rowC(m) - delta_a) * HDIM + c * 8;
      bbase[q] = (size_t)(n0 + i) * HDIM + c * 8;
    }
    for (int k0 = 0; k0 < HDIM; k0 += BK) {
      __syncthreads();
      #pragma unroll
      for (int q = 0; q < QA; ++q) {
        __builtin_amdgcn_global_load_lds(
            (const __attribute__((address_space(1))) void*)(Abf + abase[q] + k0),
            (__attribute__((address_space(3))) void*)(ldsA + (wave * 64 + q * 256) * 8),
            16, 0, 0);
        __builtin_amdgcn_global_load_lds(
            (const __attribute__((address_space(1))) void*)(Bmat + bbase[q] + k0),
            (__attribute__((address_space(3))) void*)(ldsB + (wave * 64 + q * 256) * 8),
            16, 0, 0);
      }
      __syncthreads();
      #pragma unroll
      for (int kk = 0; kk < 2; ++kk) {
        shortx8 af[NT], bfv[NT];
        #pragma unroll
        for (int ii = 0; ii < NT; ++ii) {
          int ra = wr * WT + ii * 16 + lr;
          af[ii] = *(const shortx8*)(ldsA + ra * BK + (((kk * 4 + g) ^ ((ra >> 1) & 7)) * 8));
          int rb = wc * WT + ii * 16 + lr;
          bfv[ii] = *(const shortx8*)(ldsB + rb * BK + (((kk * 4 + g) ^ ((rb >> 1) & 7)) * 8));
        }
        #pragma unroll
        for (int ii = 0; ii < NT; ++ii)
          #pragma unroll
          for (int jj = 0; jj < NT; ++jj)
            acc[ii][jj] = __builtin_amdgcn_mfma_f32_16x16x32_bf16(af[ii], bfv[jj], acc[ii][jj], 0, 0, 0);
      }
    }
  }

  // epilogue: C/D layout col = lane&15, row = (lane>>4)*4 + reg
  #pragma unroll
  for (int ii = 0; ii < NT; ++ii) {
    #pragma unroll
    for (int r = 0; r < 4; ++r) {
      int m = m0 + wr * WT + ii * 16 + g * 4 + r;
      if (m >= M) continue;
      size_t rowoff = (size_t)rowC(m) * HDIM;
      #pragma unroll
      for (int jj = 0; jj < NT; ++jj) {
        int col = n0 + wc * WT + jj * 16 + lr;
        float v = acc[ii][jj][r];
        if (Copy16) {
          us pv = zero_aop ? (us)0 : Abf[rowoff + col];
          Copy16[(size_t)(rowC(m) - delta_copy) * HDIM + col] = pv;
        }
        if (Out32) Out32[rowoff + col] = v;
        if (Out16) Out16[rowoff + col] = f2bf(v);
        if (OutH) {
          __half hv = __float2half(v);
          OutH[rowoff + col] = *(const us*)&hv;
        }
      }
    }
  }
}

// ---------------- launch ----------------
extern "C" void kernel_launch(void* const* d_in, const int* in_sizes, int n_in,
                              void* d_out, int out_size, void* d_ws, size_t ws_size,
                              hipStream_t stream) {
  const float* x  = (const float*)d_in[0];
  const float* WA = (const float*)d_in[1];
  const float* WB = (const float*)d_in[2];
  const float* WC = (const float*)d_in[3];

  float* ys = (float*)d_out;                     // [32768,1024]
  float* U  = ys + (size_t)MALL * HDIM;          // hs region (also down-sweep ping A)
  us* U16 = (us*)U;

  char* wsb = (char*)d_ws;
  int*   bar  = (int*)(wsb);                     // 3*PNB phase flags
  float* uu   = (float*)(wsb + 4096);            // 3*1024
  float* vv   = (float*)(wsb + 20480);           // 3*1024
  float* part = (float*)(wsb + 32768);           // 3*1024 norm partials
  us* An = (us*)(wsb + 65536);                   // An,Bn,Cn contiguous
  us* Bn = An + 1048576;
  us* Cn = Bn + 1048576;
  us* PT = Cn + 1048576;                         // transpose scratch + powers
  us* Ppow[9];
  Ppow[0] = An;
  for (int d = 1; d <= 8; ++d) Ppow[d] = PT + (size_t)d * 1048576;
  us* Xbf  = (us*)(wsb + 25231360);              // 64MB: x bf16, then fp16 node buffer Uh
  us* Uh   = Xbf;                                //       (x dead after step 4)
  us* U0bf = Xbf + (size_t)MALL * HDIM;          // 64MB: xb bf16; later Hbf mirror
  us* Ubf  = U0bf + (size_t)MALL * HDIM;         // 64MB: up-sweep node bf16 / ping B
  if (ws_size < 226643968ULL) return;

  auto gemm = [&](int tile, const us* A, const us* B, const us* accP,
                  float* o32, us* o16, us* oH, us* cp16,
                  int M, int slog, int da, int dacc, int dcp, int am, int za) {
    dim3 grid((M + tile - 1) / tile, HDIM / tile);
    if (tile == 128)
      k_gemm<128><<<grid, 256, 0, stream>>>(A, B, accP, o32, o16, oH, cp16, M, slog, da, dacc, dcp, am, za);
    else
      k_gemm<64><<<grid, 256, 0, stream>>>(A, B, accP, o32, o16, oH, cp16, M, slog, da, dacc, dcp, am, za);
  };

  // 1) spectral norms (one persistent kernel; phase flags zeroed per call)
  hipMemsetAsync(bar, 0, 3 * PNB * sizeof(int), stream);
  k_power<<<dim3(PNB, 3), 512, 0, stream>>>(WA, WB, WC, uu, vv, part, bar);

  // 2) casts (1/sigma folded in; sigma finalized from partials inside k_cast_mats)
  k_cast_mats<<<dim3(3072), 256, 0, stream>>>(WA, WB, WC, part, An);
  k_cast_x<<<dim3(8192), 256, 0, stream>>>(x, Xbf, 8388608);

  // 3) power chain A^(2^d), d=1..8
  for (int d = 1; d <= 8; ++d) {
    k_transpose<<<dim3(32, 32), 256, 0, stream>>>(Ppow[d - 1], PT);
    gemm(64, Ppow[d - 1], PT, nullptr, nullptr, Ppow[d], nullptr, nullptr,
         1024, 0, 0, 0, 0, 0, 0);
  }

  // 4) xb = x Bn^T -> U0bf (bf16 only)
  gemm(128, Xbf, Bn, nullptr, nullptr, U0bf, nullptr, nullptr, MALL, 0, 0, 0, 0, 0, 0);

  // 5) up-sweep: node = A^(2^d) * left + right ; bf16 nodes -> Ubf, fp16 nodes -> Uh
  for (int d = 0; d <= 8; ++d) {
    int M = MALL >> (d + 1);
    const us* srcA = (d == 0) ? U0bf : Ubf;
    const us* accP = (d == 0) ? U0bf : Uh;
    int am = (d == 0) ? 2 : 3;
    gemm(M >= 2048 ? 128 : 64, srcA, Ppow[d], accP, nullptr, Ubf, Uh, nullptr,
         M, d + 1, 1 << d, 0, 0, am, 0);
  }

  // 6) down-sweep: prefix_right = A^(2^d) prefix_par + up_left; prefix_left = prefix_par
  //    ping-pong U16 (d_out hs region) <-> Ubf; additive from Uh fp16 (U0bf bf16 at d=0)
  {
    us* PP2[2] = {U16, Ubf};        // idx even -> U16, idx odd -> Ubf; idx9 dst = Ubf
    for (int idx = 0; idx <= 9; ++idx) {
      int d = 9 - idx;
      int M = MALL >> (d + 1);
      const us* srcA = idx ? PP2[(idx - 1) & 1] : nullptr;
      us* dst = PP2[idx & 1];
      const us* accP = (d == 0) ? U0bf : Uh;
      int am = (d == 0) ? 2 : 3;
      gemm(M >= 2048 ? 128 : 64, srcA, Ppow[d], accP,
           nullptr, dst, nullptr, dst,
           M, d + 1, 0, 1 << d, 1 << d, am, idx == 0 ? 1 : 0);
    }
  }

  // 7) final apply: h_t = An * p_t + xb_t  (p in Ubf, xb in U0bf) -> hs fp32 + Hbf(->U0bf)
  gemm(128, Ubf, An, U0bf, U, U0bf, nullptr, nullptr, MALL, 0, 0, 0, 0, 2, 0);

  // 8) ys = hs Cn^T
  gemm(128, U0bf, Cn, nullptr, ys, nullptr, nullptr, nullptr, MALL, 0, 0, 0, 0, 0, 0);
}

// Round 3
// 1335.335 us; speedup vs baseline: 1.1797x; 1.0017x over previous
//
#include <hip/hip_runtime.h>
#include <hip/hip_fp16.h>
#include <stdint.h>
#include <math.h>

// RegularizedSSM: fused spectral-norm (flag-barrier persistent kernel) ->
// xb = x Bn^T -> Blelloch scan over t (bf16 A-op path + fp16 accumulator path)
// -> hs fp32 -> ys = hs Cn^T.
//
// R3: new k_gemm256 (256x256 tile, BK=32, 4-deep LDS pipeline, counted vmcnt,
// raw s_barrier, setprio) for the three full-size GEMMs (steps 4/7/8).
// Tree levels and the A-power chain keep the old BK=64 k_gemm.

typedef unsigned short us;
typedef float  floatx4 __attribute__((ext_vector_type(4)));
typedef short  shortx8 __attribute__((ext_vector_type(8)));

#define HDIM 1024
#define MALL 32768   // B*T
#define PNB  32      // power-iteration blocks per matrix

__device__ __forceinline__ us f2bf(float f) {
  union { float f; unsigned u; } v; v.f = f;
  unsigned u = v.u;
  return (us)((u + 0x7FFFu + ((u >> 16) & 1u)) >> 16);   // RNE
}
__device__ __forceinline__ float bf2f(us h) {
  union { float f; unsigned u; } v; v.u = ((unsigned)h) << 16;
  return v.f;
}

__device__ __forceinline__ float bsum32(float t) {
  #pragma unroll
  for (int o = 16; o > 0; o >>= 1) t += __shfl_xor(t, o, 32);
  return t;
}

// ---- agent-scope coherent (L2-bypass) accessors: no cache maintenance ----
__device__ __forceinline__ float gload(const float* p) {
  return __hip_atomic_load((float*)p, __ATOMIC_RELAXED, __HIP_MEMORY_SCOPE_AGENT);
}
__device__ __forceinline__ float2 gload2(const float* p) {
  unsigned long long r = __hip_atomic_load((unsigned long long*)p,
                                           __ATOMIC_RELAXED, __HIP_MEMORY_SCOPE_AGENT);
  union { unsigned long long u; float2 f; } v; v.u = r; return v.f;
}
__device__ __forceinline__ void gstore(float* p, float x) {
  __hip_atomic_store(p, x, __ATOMIC_RELAXED, __HIP_MEMORY_SCOPE_AGENT);
}

// Flag barrier: block b publishes phase number; 32 lanes poll the 32 flags.
__device__ __forceinline__ void gbar(int* flag, int b, int phase) {
  const int tid = threadIdx.x;
  __syncthreads();
  if (tid == 0)
    __hip_atomic_store(flag + b, phase, __ATOMIC_RELAXED, __HIP_MEMORY_SCOPE_AGENT);
  if (tid < PNB) {
    for (;;) {
      int f = __hip_atomic_load(flag + tid, __ATOMIC_RELAXED, __HIP_MEMORY_SCOPE_AGENT);
      if (__ballot(f < phase) == 0ULL) break;
      __builtin_amdgcn_s_sleep(2);
    }
  }
  __syncthreads();
}

// grid (PNB, 3) x 512 threads.  um/vm hold RAW (unnormalized) vectors.
__global__ void k_power(const float* __restrict__ WA, const float* __restrict__ WB,
                        const float* __restrict__ WC,
                        float* __restrict__ uu, float* __restrict__ vv,
                        float* __restrict__ part, int* __restrict__ bar) {
  const int m = blockIdx.y, b = blockIdx.x, tid = threadIdx.x;
  const float* W = m == 0 ? WA : (m == 1 ? WB : WC);
  float* um = uu + m * 1024;
  float* vm = vv + m * 1024;
  float* PV = part + m * 1024;
  float* PU = part + m * 1024 + 512;
  int* flag = bar + m * PNB;

  __shared__ __align__(16) float sh[1024];   // staged normalized vector
  __shared__ __align__(16) float red[512];
  __shared__ float bc;

  const int il = tid & 31, jp = tid >> 5;    // A: col-in-slice, row-group (16 x 64)
  const int jr = tid >> 4, ip = tid & 15;    // B: row-in-slice, k-lane

  int ph = 0;
  for (int it = 0; it <= 10; ++it) {
    // ---- stage normalized u into sh ----
    if (it == 0) {
      ((float2*)sh)[tid] = make_float2(0.03125f, 0.03125f);   // u0 = 1/sqrt(1024), unit
      __syncthreads();
    } else {
      if (tid < 32) {
        float t = bsum32(gload(PU + (it - 1) * 32 + tid));
        if (tid == 0) bc = rsqrtf(t + 1e-24f);
      }
      __syncthreads();
      float su = bc;
      float2 u2 = gload2(um + tid * 2);
      ((float2*)sh)[tid] = make_float2(u2.x * su, u2.y * su);
      __syncthreads();
    }

    // ---- phase A: v = W^T u_norm ; block owns cols [b*32, b*32+32) ----
    {
      const int col = b * 32 + il;
      const float* Wp = W + (size_t)(jp * 64) * 1024 + col;
      const float* up = sh + jp * 64;
      float a0 = 0.f, a1 = 0.f, a2 = 0.f, a3 = 0.f, a4 = 0.f, a5 = 0.f, a6 = 0.f, a7 = 0.f;
      #pragma unroll
      for (int j = 0; j < 64; j += 8) {
        a0 = fmaf(Wp[(size_t)(j + 0) * 1024], up[j + 0], a0);
        a1 = fmaf(Wp[(size_t)(j + 1) * 1024], up[j + 1], a1);
        a2 = fmaf(Wp[(size_t)(j + 2) * 1024], up[j + 2], a2);
        a3 = fmaf(Wp[(size_t)(j + 3) * 1024], up[j + 3], a3);
        a4 = fmaf(Wp[(size_t)(j + 4) * 1024], up[j + 4], a4);
        a5 = fmaf(Wp[(size_t)(j + 5) * 1024], up[j + 5], a5);
        a6 = fmaf(Wp[(size_t)(j + 6) * 1024], up[j + 6], a6);
        a7 = fmaf(Wp[(size_t)(j + 7) * 1024], up[j + 7], a7);
      }
      red[tid] = ((a0 + a1) + (a2 + a3)) + ((a4 + a5) + (a6 + a7));
      __syncthreads();
      if (tid < 32) {
        float s = 0.f;
        #pragma unroll
        for (int g = 0; g < 16; ++g) s += red[tid + 32 * g];
        gstore(vm + b * 32 + tid, s);
        float t = bsum32(s * s);
        if (tid == 0) gstore(PV + it * 32 + b, t);
      }
    }
    if (it == 10) break;            // sigma = sqrt(sum PV[10]); consumed by k_cast_mats
    gbar(flag, b, ++ph);

    // ---- stage normalized v into sh ----
    if (tid < 32) {
      float t = bsum32(gload(PV + it * 32 + tid));
      if (tid == 0) bc = rsqrtf(t + 1e-24f);
    }
    __syncthreads();
    {
      float sv = bc;
      float2 v2 = gload2(vm + tid * 2);
      ((float2*)sh)[tid] = make_float2(v2.x * sv, v2.y * sv);
    }
    __syncthreads();

    // ---- phase B: u = W v_norm ; block owns rows [b*32, b*32+32) ----
    {
      const int row = b * 32 + jr;
      const float* Wr = W + (size_t)row * 1024;
      float b0 = 0.f, b1 = 0.f, b2 = 0.f, b3 = 0.f, b4 = 0.f, b5 = 0.f, b6 = 0.f, b7 = 0.f;
      #pragma unroll
      for (int k = 0; k < 64; k += 8) {
        b0 = fmaf(Wr[ip + 16 * (k + 0)], sh[ip + 16 * (k + 0)], b0);
        b1 = fmaf(Wr[ip + 16 * (k + 1)], sh[ip + 16 * (k + 1)], b1);
        b2 = fmaf(Wr[ip + 16 * (k + 2)], sh[ip + 16 * (k + 2)], b2);
        b3 = fmaf(Wr[ip + 16 * (k + 3)], sh[ip + 16 * (k + 3)], b3);
        b4 = fmaf(Wr[ip + 16 * (k + 4)], sh[ip + 16 * (k + 4)], b4);
        b5 = fmaf(Wr[ip + 16 * (k + 5)], sh[ip + 16 * (k + 5)], b5);
        b6 = fmaf(Wr[ip + 16 * (k + 6)], sh[ip + 16 * (k + 6)], b6);
        b7 = fmaf(Wr[ip + 16 * (k + 7)], sh[ip + 16 * (k + 7)], b7);
      }
      float acc = ((b0 + b1) + (b2 + b3)) + ((b4 + b5) + (b6 + b7));
      acc += __shfl_down(acc, 8, 16);
      acc += __shfl_down(acc, 4, 16);
      acc += __shfl_down(acc, 2, 16);
      acc += __shfl_down(acc, 1, 16);
      if (ip == 0) { gstore(um + row, acc); red[jr] = acc * acc; }
      __syncthreads();
      if (tid < 32) {
        float t = bsum32(red[tid]);
        if (tid == 0) gstore(PU + it * 32 + b, t);
      }
    }
    gbar(flag, b, ++ph);
  }
}

// ---------------- casts ----------------
__global__ void k_cast_mats(const float* __restrict__ WA, const float* __restrict__ WB,
                            const float* __restrict__ WC, const float* __restrict__ part,
                            us* __restrict__ dst) {
  __shared__ float bcs;
  const int m = (int)(((unsigned)blockIdx.x * 256u) >> 18);
  if (threadIdx.x < 32) {
    float t = bsum32(part[m * 1024 + 10 * 32 + threadIdx.x]);   // ssq of final v_raw
    if (threadIdx.x == 0) bcs = rsqrtf(t + 1e-24f);             // 1/sigma
  }
  __syncthreads();
  float rs = bcs;
  int idx = blockIdx.x * 256 + threadIdx.x;
  const float* W = m == 0 ? WA : (m == 1 ? WB : WC);
  float4 v = ((const float4*)W)[idx & 262143];
  unsigned lo = f2bf(v.x * rs) | ((unsigned)f2bf(v.y * rs) << 16);
  unsigned hi = f2bf(v.z * rs) | ((unsigned)f2bf(v.w * rs) << 16);
  ((uint2*)dst)[idx] = make_uint2(lo, hi);
}

__global__ void k_cast_x(const float* __restrict__ src, us* __restrict__ dst, int n4) {
  int idx = blockIdx.x * 256 + threadIdx.x;
  int stride = gridDim.x * 256;
  for (; idx < n4; idx += stride) {
    float4 v = ((const float4*)src)[idx];
    unsigned lo = f2bf(v.x) | ((unsigned)f2bf(v.y) << 16);
    unsigned hi = f2bf(v.z) | ((unsigned)f2bf(v.w) << 16);
    ((uint2*)dst)[idx] = make_uint2(lo, hi);
  }
}

// bf16 1024x1024 transpose
__global__ void k_transpose(const us* __restrict__ src, us* __restrict__ dst) {
  __shared__ us t[32][33];
  int bx = blockIdx.x * 32, by = blockIdx.y * 32;
  int tx = threadIdx.x & 31, ty = threadIdx.x >> 5;
  for (int r = ty; r < 32; r += 8)
    t[r][tx] = src[(size_t)(by + r) * 1024 + bx + tx];
  __syncthreads();
  for (int r = ty; r < 32; r += 8)
    dst[(size_t)(bx + r) * 1024 + by + tx] = t[tx][r];
}

// ---------------- GEMM (legacy BK=64, 128/64 tile) for tree + power chain ----------------
// accmode: 0 zero, 2 bf16 acc, 3 fp16 acc.
template <int TILE>
__global__ __launch_bounds__(256, 3)
void k_gemm(const us* __restrict__ Abf, const us* __restrict__ Bmat,
            const us* __restrict__ AccP,
            float* __restrict__ Out32, us* __restrict__ Out16, us* __restrict__ OutH,
            us* __restrict__ Copy16,
            int M, int stride_log, int delta_a, int delta_acc, int delta_copy,
            int accmode, int zero_aop) {
  constexpr int BK = 64;
  constexpr int WT = TILE / 2;   // wave tile
  constexpr int NT = WT / 16;    // mfma tiles per wave dim
  constexpr int QA = TILE / 32;  // 16B staging chunks per thread per operand

  __shared__ us ldsA[TILE * BK];
  __shared__ us ldsB[TILE * BK];

  const int tid = threadIdx.x;
  const int wave = tid >> 6, lane = tid & 63;
  const int wr = wave >> 1, wc = wave & 1;
  const int lr = lane & 15, g = lane >> 4;
  const int m0 = blockIdx.x * TILE, n0 = blockIdx.y * TILE;

  const int cnt_log = 10 - stride_log;
  const int cnt_mask = (1 << cnt_log) - 1;
  auto rowC = [&](int m) -> int {
    int j = m & cnt_mask, b = m >> cnt_log;
    return (b << 10) + (((j + 1) << stride_log) - 1);
  };

  floatx4 acc[NT][NT];
  if (accmode == 0) {
    #pragma unroll
    for (int i = 0; i < NT; ++i)
      #pragma unroll
      for (int j = 0; j < NT; ++j) acc[i][j] = (floatx4)(0.0f);
  } else {
    #pragma unroll
    for (int ii = 0; ii < NT; ++ii) {
      #pragma unroll
      for (int r = 0; r < 4; ++r) {
        int m = m0 + wr * WT + ii * 16 + g * 4 + r;
        if (m >= M) m = M - 1;
        size_t rowoff = (size_t)(rowC(m) - delta_acc) * HDIM;
        #pragma unroll
        for (int jj = 0; jj < NT; ++jj) {
          int col = n0 + wc * WT + jj * 16 + lr;
          us raw = AccP[rowoff + col];
          acc[ii][jj][r] = (accmode == 2) ? bf2f(raw)
                                          : __half2float(*(const __half*)&raw);
        }
      }
    }
  }

  if (!zero_aop) {
    size_t abase[QA], bbase[QA];
    #pragma unroll
    for (int q = 0; q < QA; ++q) {
      int ch = tid + q * 256;
      int i = ch >> 3;
      int c = (ch & 7) ^ ((i >> 1) & 7);
      int m = m0 + i; if (m >= M) m = M - 1;
      abase[q] = (size_t)(rowC(m) - delta_a) * HDIM + c * 8;
      bbase[q] = (size_t)(n0 + i) * HDIM + c * 8;
    }
    for (int k0 = 0; k0 < HDIM; k0 += BK) {
      __syncthreads();
      #pragma unroll
      for (int q = 0; q < QA; ++q) {
        __builtin_amdgcn_global_load_lds(
            (const __attribute__((address_space(1))) void*)(Abf + abase[q] + k0),
            (__attribute__((address_space(3))) void*)(ldsA + (wave * 64 + q * 256) * 8),
            16, 0, 0);
        __builtin_amdgcn_global_load_lds(
            (const __attribute__((address_space(1))) void*)(Bmat + bbase[q] + k0),
            (__attribute__((address_space(3))) void*)(ldsB + (wave * 64 + q * 256) * 8),
            16, 0, 0);
      }
      __syncthreads();
      #pragma unroll
      for (int kk = 0; kk < 2; ++kk) {
        shortx8 af[NT], bfv[NT];
        #pragma unroll
        for (int ii = 0; ii < NT; ++ii) {
          int ra = wr * WT + ii * 16 + lr;
          af[ii] = *(const shortx8*)(ldsA + ra * BK + (((kk * 4 + g) ^ ((ra >> 1) & 7)) * 8));
          int rb = wc * WT + ii * 16 + lr;
          bfv[ii] = *(const shortx8*)(ldsB + rb * BK + (((kk * 4 + g) ^ ((rb >> 1) & 7)) * 8));
        }
        #pragma unroll
        for (int ii = 0; ii < NT; ++ii)
          #pragma unroll
          for (int jj = 0; jj < NT; ++jj)
            acc[ii][jj] = __builtin_amdgcn_mfma_f32_16x16x32_bf16(af[ii], bfv[jj], acc[ii][jj], 0, 0, 0);
      }
    }
  }

  // epilogue: C/D layout col = lane&15, row = (lane>>4)*4 + reg
  #pragma unroll
  for (int ii = 0; ii < NT; ++ii) {
    #pragma unroll
    for (int r = 0; r < 4; ++r) {
      int m = m0 + wr * WT + ii * 16 + g * 4 + r;
      if (m >= M) continue;
      size_t rowoff = (size_t)rowC(m) * HDIM;
      #pragma unroll
      for (int jj = 0; jj < NT; ++jj) {
        int col = n0 + wc * WT + jj * 16 + lr;
        float v = acc[ii][jj][r];
        if (Copy16) {
          us pv = zero_aop ? (us)0 : Abf[rowoff + col];
          Copy16[(size_t)(rowC(m) - delta_copy) * HDIM + col] = pv;
        }
        if (Out32) Out32[rowoff + col] = v;
        if (Out16) Out16[rowoff + col] = f2bf(v);
        if (OutH) {
          __half hv = __float2half(v);
          OutH[rowoff + col] = *(const us*)&hv;
        }
      }
    }
  }
}

// ---------------- k_gemm256: 256x256 tile, BK=32, 4-deep pipelined ----------------
// C[m,n] = sum_k A[m,k]*B[n,k] (+ optional bf16 Acc added in epilogue).
// 512 threads = 8 waves (2M x 4N); per-wave 128x64 output (8x4 16x16 frags).
// LDS: 4 buffers x (A 16KB + B 16KB) = 128 KiB. Counted vmcnt, raw s_barrier.
// LDS layout (per buffer, per operand): pair-line — rows 2l,2l+1 share a 128B
// line of 8x16B chunks; chunk phi at line l holds (row=2l+(psi>>2), kchunk=psi&3),
// psi = phi ^ (l&7).  2-way bank dispersion on ds_read_b128 (free).
#define NK256 32   // K / 32

__global__ __launch_bounds__(512, 2)
void k_gemm256(const us* __restrict__ Abf, const us* __restrict__ Bmat,
               const us* __restrict__ AccP,
               float* __restrict__ Out32, us* __restrict__ Out16) {
  __shared__ __align__(16) us lds[4][2][8192];   // [buf][A/B][256*32]

  const int tid = threadIdx.x;
  const int wave = tid >> 6, lane = tid & 63;
  const int wr = wave >> 2, wc = wave & 3;       // 2 x 4 wave grid
  const int lr = lane & 15, g = lane >> 4;

  // XCD-chunked block swizzle: the 4 column-siblings (same A panel) adjacent.
  const int nwg = gridDim.x * gridDim.y;
  int lid = blockIdx.x + blockIdx.y * gridDim.x;
  int s = (lid & 7) * (nwg >> 3) + (lid >> 3);
  const int m0 = (s >> 2) * 256, n0 = (s & 3) * 256;

  // staging sources: kappa = q*512 + tid -> (row, kchunk) via pair-line map
  const us* srcA[2]; const us* srcB[2]; int ldst[2];
  #pragma unroll
  for (int q = 0; q < 2; ++q) {
    int kappa = q * 512 + tid;
    int l = kappa >> 3, phi = kappa & 7, psi = phi ^ (l & 7);
    int row = 2 * l + (psi >> 2), c = psi & 3;
    srcA[q] = Abf + (size_t)(m0 + row) * HDIM + c * 8;
    srcB[q] = Bmat + (size_t)(n0 + row) * HDIM + c * 8;
    ldst[q] = (q * 512 + wave * 64) * 8;   // wave-uniform dest base (elems)
  }

  auto stage = [&](int kt) {
    const int bi = kt & 3;
    const int ko = kt * 32;
    #pragma unroll
    for (int q = 0; q < 2; ++q) {
      __builtin_amdgcn_global_load_lds(
          (const __attribute__((address_space(1))) void*)(srcA[q] + ko),
          (__attribute__((address_space(3))) void*)(&lds[bi][0][0] + ldst[q]), 16, 0, 0);
      __builtin_amdgcn_global_load_lds(
          (const __attribute__((address_space(1))) void*)(srcB[q] + ko),
          (__attribute__((address_space(3))) void*)(&lds[bi][1][0] + ldst[q]), 16, 0, 0);
    }
  };

  floatx4 acc[8][4];
  #pragma unroll
  for (int i = 0; i < 8; ++i)
    #pragma unroll
    for (int j = 0; j < 4; ++j) acc[i][j] = (floatx4)(0.0f);

  // prologue: 3 tiles in flight, retire tile 0 (4 loads/thread/tile)
  stage(0); stage(1); stage(2);
  asm volatile("s_waitcnt vmcnt(8)" ::: "memory");

  for (int kt = 0; kt < NK256; ++kt) {
    asm volatile("" ::: "memory");
    __builtin_amdgcn_s_barrier();
    asm volatile("" ::: "memory");
    if (kt + 3 < NK256) stage(kt + 3);
    const int bi = kt & 3;

    shortx8 bq[4];
    #pragma unroll
    for (int jj = 0; jj < 4; ++jj) {
      int rb = wc * 64 + jj * 16 + lr;
      int phi = ((((rb & 1) << 2) | g) ^ ((rb >> 1) & 7));
      bq[jj] = *(const shortx8*)(&lds[bi][1][(rb >> 1) * 64 + phi * 8]);
    }
    __builtin_amdgcn_s_setprio(1);
    #pragma unroll
    for (int ii = 0; ii < 8; ++ii) {
      int ra = wr * 128 + ii * 16 + lr;
      int phi = ((((ra & 1) << 2) | g) ^ ((ra >> 1) & 7));
      shortx8 aq = *(const shortx8*)(&lds[bi][0][(ra >> 1) * 64 + phi * 8]);
      #pragma unroll
      for (int jj = 0; jj < 4; ++jj)
        acc[ii][jj] = __builtin_amdgcn_mfma_f32_16x16x32_bf16(aq, bq[jj], acc[ii][jj], 0, 0, 0);
    }
    __builtin_amdgcn_s_setprio(0);

    if (kt < NK256 - 3)       asm volatile("s_waitcnt vmcnt(8)" ::: "memory");
    else if (kt == NK256 - 3) asm volatile("s_waitcnt vmcnt(4)" ::: "memory");
    else if (kt == NK256 - 2) asm volatile("s_waitcnt vmcnt(0)" ::: "memory");
  }

  // epilogue: C/D layout col = lane&15, row = (lane>>4)*4 + reg.
  // Acc (bf16) added here instead of pre-initializing (keeps the counted
  // vmcnt stream clean; same sum, different rounding order only).
  #pragma unroll
  for (int ii = 0; ii < 8; ++ii) {
    #pragma unroll
    for (int r = 0; r < 4; ++r) {
      int mrow = m0 + wr * 128 + ii * 16 + g * 4 + r;
      size_t rowoff = (size_t)mrow * HDIM;
      #pragma unroll
      for (int jj = 0; jj < 4; ++jj) {
        int col = n0 + wc * 64 + jj * 16 + lr;
        float v = acc[ii][jj][r];
        if (AccP) v += bf2f(AccP[rowoff + col]);
        if (Out32) Out32[rowoff + col] = v;
        if (Out16) Out16[rowoff + col] = f2bf(v);
      }
    }
  }
}

// ---------------- launch ----------------
extern "C" void kernel_launch(void* const* d_in, const int* in_sizes, int n_in,
                              void* d_out, int out_size, void* d_ws, size_t ws_size,
                              hipStream_t stream) {
  const float* x  = (const float*)d_in[0];
  const float* WA = (const float*)d_in[1];
  const float* WB = (const float*)d_in[2];
  const float* WC = (const float*)d_in[3];

  float* ys = (float*)d_out;                     // [32768,1024]
  float* U  = ys + (size_t)MALL * HDIM;          // hs region (also down-sweep ping A)
  us* U16 = (us*)U;

  char* wsb = (char*)d_ws;
  int*   bar  = (int*)(wsb);                     // 3*PNB phase flags
  float* uu   = (float*)(wsb + 4096);            // 3*1024
  float* vv   = (float*)(wsb + 20480);           // 3*1024
  float* part = (float*)(wsb + 32768);           // 3*1024 norm partials
  us* An = (us*)(wsb + 65536);                   // An,Bn,Cn contiguous
  us* Bn = An + 1048576;
  us* Cn = Bn + 1048576;
  us* PT = Cn + 1048576;                         // transpose scratch + powers
  us* Ppow[9];
  Ppow[0] = An;
  for (int d = 1; d <= 8; ++d) Ppow[d] = PT + (size_t)d * 1048576;
  us* Xbf  = (us*)(wsb + 25231360);              // 64MB: x bf16, then fp16 node buffer Uh
  us* Uh   = Xbf;                                //       (x dead after step 4)
  us* U0bf = Xbf + (size_t)MALL * HDIM;          // 64MB: xb bf16; later Hbf mirror
  us* Ubf  = U0bf + (size_t)MALL * HDIM;         // 64MB: up-sweep node bf16 / ping B
  if (ws_size < 226643968ULL) return;

  auto gemm = [&](int tile, const us* A, const us* B, const us* accP,
                  float* o32, us* o16, us* oH, us* cp16,
                  int M, int slog, int da, int dacc, int dcp, int am, int za) {
    dim3 grid((M + tile - 1) / tile, HDIM / tile);
    if (tile == 128)
      k_gemm<128><<<grid, 256, 0, stream>>>(A, B, accP, o32, o16, oH, cp16, M, slog, da, dacc, dcp, am, za);
    else
      k_gemm<64><<<grid, 256, 0, stream>>>(A, B, accP, o32, o16, oH, cp16, M, slog, da, dacc, dcp, am, za);
  };
  auto gemm256 = [&](const us* A, const us* B, const us* accP, float* o32, us* o16) {
    k_gemm256<<<dim3(MALL / 256, 4), 512, 0, stream>>>(A, B, accP, o32, o16);
  };

  // 1) spectral norms (one persistent kernel; phase flags zeroed per call)
  hipMemsetAsync(bar, 0, 3 * PNB * sizeof(int), stream);
  k_power<<<dim3(PNB, 3), 512, 0, stream>>>(WA, WB, WC, uu, vv, part, bar);

  // 2) casts (1/sigma folded in; sigma finalized from partials inside k_cast_mats)
  k_cast_mats<<<dim3(3072), 256, 0, stream>>>(WA, WB, WC, part, An);
  k_cast_x<<<dim3(8192), 256, 0, stream>>>(x, Xbf, 8388608);

  // 3) power chain A^(2^d), d=1..8
  for (int d = 1; d <= 8; ++d) {
    k_transpose<<<dim3(32, 32), 256, 0, stream>>>(Ppow[d - 1], PT);
    gemm(64, Ppow[d - 1], PT, nullptr, nullptr, Ppow[d], nullptr, nullptr,
         1024, 0, 0, 0, 0, 0, 0);
  }

  // 4) xb = x Bn^T -> U0bf (bf16 only)
  gemm256(Xbf, Bn, nullptr, nullptr, U0bf);

  // 5) up-sweep: node = A^(2^d) * left + right ; bf16 nodes -> Ubf, fp16 nodes -> Uh
  for (int d = 0; d <= 8; ++d) {
    int M = MALL >> (d + 1);
    const us* srcA = (d == 0) ? U0bf : Ubf;
    const us* accP = (d == 0) ? U0bf : Uh;
    int am = (d == 0) ? 2 : 3;
    gemm(M >= 2048 ? 128 : 64, srcA, Ppow[d], accP, nullptr, Ubf, Uh, nullptr,
         M, d + 1, 1 << d, 0, 0, am, 0);
  }

  // 6) down-sweep: prefix_right = A^(2^d) prefix_par + up_left; prefix_left = prefix_par
  {
    us* PP2[2] = {U16, Ubf};        // idx even -> U16, idx odd -> Ubf; idx9 dst = Ubf
    for (int idx = 0; idx <= 9; ++idx) {
      int d = 9 - idx;
      int M = MALL >> (d + 1);
      const us* srcA = idx ? PP2[(idx - 1) & 1] : nullptr;
      us* dst = PP2[idx & 1];
      const us* accP = (d == 0) ? U0bf : Uh;
      int am = (d == 0) ? 2 : 3;
      gemm(M >= 2048 ? 128 : 64, srcA, Ppow[d], accP,
           nullptr, dst, nullptr, dst,
           M, d + 1, 0, 1 << d, 1 << d, am, idx == 0 ? 1 : 0);
    }
  }

  // 7) final apply: h_t = An * p_t + xb_t  (p in Ubf, xb in U0bf) -> hs fp32 + Hbf(->U0bf)
  gemm256(Ubf, An, U0bf, U, U0bf);

  // 8) ys = hs Cn^T
  gemm256(U0bf, Cn, nullptr, ys, nullptr);
}